// Round 11
// baseline (363.815 us; speedup 1.0000x reference)
//
#include <hip/hip_runtime.h>
#include <hip/hip_fp16.h>

#define HDIM 32
#define IN_DIM 128
#define NEG_SLOPE 0.2f
#define NPB 128            // nodes per coarse bucket (power of 2)
#define NPB_SHIFT 7
#define MAXB 1024          // max buckets (B = ceil(N/128) = 782)
#define CHUNK 8192         // edges per chunk block
#define CAP 4096           // max records per bucket for LDS sort fast path

typedef _Float16 half8  __attribute__((ext_vector_type(8)));
typedef _Float16 half4v __attribute__((ext_vector_type(4)));
typedef float    floatx4 __attribute__((ext_vector_type(4)));

__device__ __forceinline__ float leaky(float e) {
    return (e >= 0.f) ? e : NEG_SLOPE * e;
}

__device__ __forceinline__ float2 h2f(unsigned int u) {
    __half2 h = *reinterpret_cast<__half2*>(&u);
    return __half22float2(h);
}

// ------------- MFMA GEMM (layer 1 only): h = x@W fp16 out ----------------

template<int K>
__global__ __launch_bounds__(256) void gemm_mfma(
    const float* __restrict__ x, const float* __restrict__ W,
    __half* __restrict__ h, int N)
{
    constexpr int KP = K + 8;                 // +8 halves pad -> 2-way conflicts only
    __shared__ _Float16 xs[64 * KP];
    __shared__ _Float16 Wt[32 * KP];          // Wt[n][k] = W[k][n]
    const int tid = threadIdx.x;
    for (int i = tid; i < K * 32; i += 256) {
        int k = i >> 5, n = i & 31;
        Wt[n * KP + k] = (_Float16)W[i];
    }
    const int lane = tid & 63;
    const int wave = tid >> 6;                // 0..3
    const int m16  = lane & 15;
    const int quad = lane >> 4;               // 0..3

    const int ntiles = (N + 63) >> 6;
    for (int tile = blockIdx.x; tile < ntiles; tile += gridDim.x) {
        const int row0 = tile << 6;
        __syncthreads();
        for (int i = tid; i < 64 * (K / 4); i += 256) {
            int r  = i / (K / 4);
            int c4 = i % (K / 4);
            float4 v = (row0 + r < N) ? ((const float4*)x)[(size_t)(row0 + r) * (K / 4) + c4]
                                      : make_float4(0.f, 0.f, 0.f, 0.f);
            half4v hv = { (_Float16)v.x, (_Float16)v.y, (_Float16)v.z, (_Float16)v.w };
            *(half4v*)&xs[r * KP + c4 * 4] = hv;
        }
        __syncthreads();
        floatx4 acc0 = {0.f, 0.f, 0.f, 0.f}, acc1 = {0.f, 0.f, 0.f, 0.f};
        const int rbase = wave * 16;
        #pragma unroll
        for (int kt = 0; kt < K / 32; kt++) {
            half8 a  = *(half8*)&xs[(rbase + m16) * KP + kt * 32 + quad * 8];
            half8 b0 = *(half8*)&Wt[m16 * KP + kt * 32 + quad * 8];
            half8 b1 = *(half8*)&Wt[(m16 + 16) * KP + kt * 32 + quad * 8];
            acc0 = __builtin_amdgcn_mfma_f32_16x16x32_f16(a, b0, acc0, 0, 0, 0);
            acc1 = __builtin_amdgcn_mfma_f32_16x16x32_f16(a, b1, acc1, 0, 0, 0);
        }
        #pragma unroll
        for (int r = 0; r < 4; r++) {
            int row = row0 + rbase + quad * 4 + r;
            if (row < N) {
                h[(size_t)row * HDIM + m16]      = __float2half(acc0[r]);
                h[(size_t)row * HDIM + m16 + 16] = __float2half(acc1[r]);
            }
        }
    }
}

// ---------------- Two-level CSR build (once per call) ----------------

__global__ __launch_bounds__(256) void chunk_hist(
    const int* __restrict__ dsts, int E, int B, int* __restrict__ cnt2D)
{
    __shared__ int hist[MAXB];
    const int blk = blockIdx.x;
    for (int i = threadIdx.x; i < B; i += 256) hist[i] = 0;
    __syncthreads();
    const int e0 = blk * CHUNK;
    for (int i = threadIdx.x; i < CHUNK; i += 256) {
        int e = e0 + i;
        if (e < E) atomicAdd(&hist[dsts[e] >> NPB_SHIFT], 1);
    }
    __syncthreads();
    for (int i = threadIdx.x; i < B; i += 256) cnt2D[(size_t)blk * B + i] = hist[i];
}

__global__ __launch_bounds__(256) void chunk_scan(
    const int* __restrict__ cnt2D, int NBLK, int B,
    int* __restrict__ off2D, int* __restrict__ bcnt)
{
    __shared__ int s[256];
    const int b = blockIdx.x, t = threadIdx.x;
    int v = (t < NBLK) ? cnt2D[(size_t)t * B + b] : 0;
    s[t] = v;
    __syncthreads();
    for (int off = 1; off < 256; off <<= 1) {
        int add = (t >= off) ? s[t - off] : 0;
        __syncthreads();
        s[t] += add;
        __syncthreads();
    }
    if (t < NBLK) off2D[(size_t)t * B + b] = s[t] - v;
    if (t == 255) bcnt[b] = s[255];
}

__global__ __launch_bounds__(1024) void bucket_scan(
    const int* __restrict__ bcnt, int B, int E,
    int* __restrict__ bstart, int* __restrict__ rowptr, int N)
{
    __shared__ int s[1024];
    const int t = threadIdx.x;
    int v = (t < B) ? bcnt[t] : 0;
    s[t] = v;
    __syncthreads();
    for (int off = 1; off < 1024; off <<= 1) {
        int add = (t >= off) ? s[t - off] : 0;
        __syncthreads();
        s[t] += add;
        __syncthreads();
    }
    if (t < B) bstart[t] = s[t] - v;
    if (t == 0) { bstart[B] = E; rowptr[N] = E; }
}

__global__ __launch_bounds__(256) void pair_scatter2(
    const int* __restrict__ srcs, const int* __restrict__ dsts, int E, int B,
    const int* __restrict__ off2D, const int* __restrict__ bstart,
    int* __restrict__ pairs)
{
    __shared__ int cur[MAXB];
    const int blk = blockIdx.x;
    for (int i = threadIdx.x; i < B; i += 256)
        cur[i] = bstart[i] + off2D[(size_t)blk * B + i];
    __syncthreads();
    const int e0 = blk * CHUNK;
    for (int i = threadIdx.x; i < CHUNK; i += 256) {
        int e = e0 + i;
        if (e < E) {
            int s = srcs[e], d = dsts[e];
            int pos = atomicAdd(&cur[d >> NPB_SHIFT], 1);
            pairs[pos] = (s << NPB_SHIFT) | (d & (NPB - 1));
        }
    }
}

__global__ __launch_bounds__(256) void bucket_sort(
    const int* __restrict__ pairs, const int* __restrict__ bstart,
    int* __restrict__ rowptr, int* __restrict__ csrsrc, int N)
{
    __shared__ int ldeg[NPB];
    __shared__ int lex[NPB];
    __shared__ int recs[CAP];
    __shared__ int sorted[CAP];
    const int b = blockIdx.x, t = threadIdx.x;
    const int p0 = bstart[b], p1 = bstart[b + 1];
    const int cnt = p1 - p0;
    if (t < NPB) ldeg[t] = 0;
    __syncthreads();
    for (int i = t; i < cnt; i += 256) {
        int r = pairs[p0 + i];
        atomicAdd(&ldeg[r & (NPB - 1)], 1);
        if (i < CAP) recs[i] = r;
    }
    __syncthreads();
    if (t < NPB) lex[t] = ldeg[t];
    __syncthreads();
    for (int off = 1; off < NPB; off <<= 1) {
        int add = (t >= off && t < NPB) ? lex[t - off] : 0;
        __syncthreads();
        if (t < NPB) lex[t] += add;
        __syncthreads();
    }
    const int node0 = b * NPB;
    if (t < NPB) {
        int excl = lex[t] - ldeg[t];
        if (node0 + t < N) rowptr[node0 + t] = p0 + excl;
        ldeg[t] = excl;
    }
    __syncthreads();
    if (cnt <= CAP) {
        for (int i = t; i < cnt; i += 256) {
            int r = recs[i];
            int pos = atomicAdd(&ldeg[r & (NPB - 1)], 1);
            sorted[pos] = r >> NPB_SHIFT;
        }
        __syncthreads();
        for (int i = t; i < cnt; i += 256) csrsrc[p0 + i] = sorted[i];
    } else {
        for (int i = t; i < cnt; i += 256) {
            int r = pairs[p0 + i];
            int pos = atomicAdd(&ldeg[r & (NPB - 1)], 1);
            csrsrc[p0 + pos] = r >> NPB_SHIFT;
        }
    }
}

// -------- Fused aggregation + next-layer GEMM --------------------------
// 4 lanes/node. es/ed recomputed in-register from fp16 h (R10 showed this is
// numerically free). For !LAST: epilogue computes h' = (out+bias) @ W_next in
// registers (32 width-4 shuffles + LDS W reads) and writes fp16 h' directly —
// no separate gemm32 dispatch, no fp32 out round-trip.

template<bool LAST>
__global__ __launch_bounds__(256) void agg_fused(
    const __half* __restrict__ h,
    const int* __restrict__ rowptr, const int* __restrict__ csrsrc,
    const float* __restrict__ a_s, const float* __restrict__ a_d,
    const float* __restrict__ b, const float* __restrict__ Wn,
    __half* __restrict__ hn, float* __restrict__ outbuf, int N)
{
    __shared__ float Ws[HDIM * HDIM];         // next-layer W, [k][c]
    if (!LAST) {
        for (int i = threadIdx.x; i < HDIM * HDIM; i += 256) Ws[i] = Wn[i];
        __syncthreads();
    }

    const int gid  = blockIdx.x * 256 + threadIdx.x;
    const int node = gid >> 2;
    const int l    = threadIdx.x & 3;
    if (node >= N) return;

    const int e0 = rowptr[node];
    const int e1 = rowptr[node + 1];
    const uint4* __restrict__ h16 = (const uint4*)h;

    float asf[8], adf[8];
    #pragma unroll
    for (int i = 0; i < 8; i++) { asf[i] = a_s[l * 8 + i]; adf[i] = a_d[l * 8 + i]; }

    // own row: ed_i and self es, row kept for self-loop accumulate
    uint4 uself = h16[(size_t)node * 4 + l];
    float2 g0 = h2f(uself.x), g1 = h2f(uself.y), g2 = h2f(uself.z), g3 = h2f(uself.w);
    float dsl = asf[0]*g0.x + asf[1]*g0.y + asf[2]*g1.x + asf[3]*g1.y
              + asf[4]*g2.x + asf[5]*g2.y + asf[6]*g3.x + asf[7]*g3.y;
    float ddl = adf[0]*g0.x + adf[1]*g0.y + adf[2]*g1.x + adf[3]*g1.y
              + adf[4]*g2.x + adf[5]*g2.y + adf[6]*g3.x + adf[7]*g3.y;
    dsl += __shfl_xor(dsl, 1); dsl += __shfl_xor(dsl, 2);
    ddl += __shfl_xor(ddl, 1); ddl += __shfl_xor(ddl, 2);
    const float edi = ddl;

    float a0=0.f,a1=0.f,a2=0.f,a3=0.f,a4=0.f,a5=0.f,a6=0.f,a7=0.f,den=0.f;

    int e = e0;
    for (; e + 8 <= e1; e += 8) {
        int s[8]; uint4 u[8];
        #pragma unroll
        for (int j = 0; j < 8; j++) s[j] = csrsrc[e + j];
        #pragma unroll
        for (int j = 0; j < 8; j++) u[j] = h16[(size_t)s[j] * 4 + l];
        #pragma unroll
        for (int j = 0; j < 8; j++) {
            float2 f0 = h2f(u[j].x), f1 = h2f(u[j].y), f2 = h2f(u[j].z), f3 = h2f(u[j].w);
            float dot = asf[0]*f0.x + asf[1]*f0.y + asf[2]*f1.x + asf[3]*f1.y
                      + asf[4]*f2.x + asf[5]*f2.y + asf[6]*f3.x + asf[7]*f3.y;
            dot += __shfl_xor(dot, 1);
            dot += __shfl_xor(dot, 2);
            float w = __expf(leaky(dot + edi));
            den += w;
            a0 += w*f0.x; a1 += w*f0.y; a2 += w*f1.x; a3 += w*f1.y;
            a4 += w*f2.x; a5 += w*f2.y; a6 += w*f3.x; a7 += w*f3.y;
        }
    }
    for (; e < e1; e++) {
        int s = csrsrc[e];
        uint4 u = h16[(size_t)s * 4 + l];
        float2 f0 = h2f(u.x), f1 = h2f(u.y), f2 = h2f(u.z), f3 = h2f(u.w);
        float dot = asf[0]*f0.x + asf[1]*f0.y + asf[2]*f1.x + asf[3]*f1.y
                  + asf[4]*f2.x + asf[5]*f2.y + asf[6]*f3.x + asf[7]*f3.y;
        dot += __shfl_xor(dot, 1);
        dot += __shfl_xor(dot, 2);
        float w = __expf(leaky(dot + edi));
        den += w;
        a0 += w*f0.x; a1 += w*f0.y; a2 += w*f1.x; a3 += w*f1.y;
        a4 += w*f2.x; a5 += w*f2.y; a6 += w*f3.x; a7 += w*f3.y;
    }
    {   // self-loop (row already in registers)
        float w = __expf(leaky(dsl + edi));
        den += w;
        a0 += w*g0.x; a1 += w*g0.y; a2 += w*g1.x; a3 += w*g1.y;
        a4 += w*g2.x; a5 += w*g2.y; a6 += w*g3.x; a7 += w*g3.y;
    }

    const float4* b4 = (const float4*)b;
    float4 bv0 = b4[2*l], bv1 = b4[2*l + 1];
    float inv = 1.f / den;
    float o[8];
    o[0] = a0*inv + bv0.x; o[1] = a1*inv + bv0.y; o[2] = a2*inv + bv0.z; o[3] = a3*inv + bv0.w;
    o[4] = a4*inv + bv1.x; o[5] = a5*inv + bv1.y; o[6] = a6*inv + bv1.z; o[7] = a7*inv + bv1.w;

    if (LAST) {
        float4 o0 = { o[0], o[1], o[2], o[3] };
        float4 o1 = { o[4], o[5], o[6], o[7] };
        ((float4*)outbuf)[(size_t)node*8 + 2*l]     = o0;
        ((float4*)outbuf)[(size_t)node*8 + 2*l + 1] = o1;
    } else {
        // replicate full out-row across the 4-lane group (width-4 shuffles)
        float row[32];
        #pragma unroll
        for (int bb = 0; bb < 4; bb++) {
            #pragma unroll
            for (int j = 0; j < 8; j++) row[bb*8 + j] = __shfl(o[j], bb, 4);
        }
        // h'_c = sum_k row[k] * W[k][c], c in [l*8, l*8+8)
        float hn8[8] = {0.f,0.f,0.f,0.f,0.f,0.f,0.f,0.f};
        #pragma unroll
        for (int k = 0; k < 32; k++) {
            float4 wa = *(const float4*)&Ws[k*32 + l*8];
            float4 wb = *(const float4*)&Ws[k*32 + l*8 + 4];
            float rk = row[k];
            hn8[0] += rk*wa.x; hn8[1] += rk*wa.y; hn8[2] += rk*wa.z; hn8[3] += rk*wa.w;
            hn8[4] += rk*wb.x; hn8[5] += rk*wb.y; hn8[6] += rk*wb.z; hn8[7] += rk*wb.w;
        }
        half8 v = { (_Float16)hn8[0], (_Float16)hn8[1], (_Float16)hn8[2], (_Float16)hn8[3],
                    (_Float16)hn8[4], (_Float16)hn8[5], (_Float16)hn8[6], (_Float16)hn8[7] };
        *(half8*)((_Float16*)hn + (size_t)node*32 + l*8) = v;
    }
}

// -------- Pool: one 64-lane wave per graph (batch sorted, binary search) ---

__global__ __launch_bounds__(256) void pool_graph(
    const float* __restrict__ x, const int* __restrict__ batch,
    float* __restrict__ out, int N, int G)
{
    const int g = (blockIdx.x * 256 + threadIdx.x) >> 6;   // wave id = graph id
    if (g >= G) return;
    const int lane = threadIdx.x & 63;
    const int feat = lane & 31;
    const int half = lane >> 5;

    int lo = 0, hi = N;
    while (lo < hi) { int mid = (lo + hi) >> 1; if (batch[mid] < g) lo = mid + 1; else hi = mid; }
    const int start = lo;
    int lo2 = start, hi2 = N;
    while (lo2 < hi2) { int mid = (lo2 + hi2) >> 1; if (batch[mid] < g + 1) lo2 = mid + 1; else hi2 = mid; }
    const int end = lo2;

    float acc = 0.f;
    for (int i = start + half; i < end; i += 2)
        acc += x[(size_t)i * HDIM + feat];
    acc += __shfl_xor(acc, 32);
    if (half == 0) {
        float cnt = (float)(end - start);
        out[(size_t)g * HDIM + feat] = acc / fmaxf(cnt, 1.f);
    }
}

// ---------------- Launch ----------------

extern "C" void kernel_launch(void* const* d_in, const int* in_sizes, int n_in,
                              void* d_out, int out_size, void* d_ws, size_t ws_size,
                              hipStream_t stream) {
    const float* x          = (const float*)d_in[0];
    const int*   edge_index = (const int*)d_in[1];
    const int*   batch      = (const int*)d_in[2];

    const int N = in_sizes[2];              // 100000
    const int E = in_sizes[1] / 2;          // 1600000
    const int G = out_size / HDIM;          // 2048
    const int B = (N + NPB - 1) / NPB;      // 782 buckets
    const int NBLK = (E + CHUNK - 1) / CHUNK;
    const int ntiles = (N + 63) / 64;

    const int* srcs = edge_index;
    const int* dsts = edge_index + E;

    // workspace layout (16B-aligned offsets)
    char* p = (char*)d_ws;
    __half* h_a   = (__half*)p; p += (size_t)N * HDIM * sizeof(__half);
    __half* h_b   = (__half*)p; p += (size_t)N * HDIM * sizeof(__half);
    float* xbuf   = (float*)p; p += (size_t)N * HDIM * sizeof(float);
    int*   rowptr = (int*)p;   p += (size_t)(N + 1) * sizeof(int);
    p += 16 - ((size_t)p & 15);
    int*   csrsrc = (int*)p;   p += (size_t)E * sizeof(int);
    int*   pairs  = (int*)p;   p += (size_t)E * sizeof(int);
    int*   cnt2D  = (int*)p;   p += (size_t)NBLK * B * sizeof(int);
    int*   off2D  = (int*)p;   p += (size_t)NBLK * B * sizeof(int);
    int*   bcnt   = (int*)p;   p += (size_t)B * sizeof(int);
    int*   bstart = (int*)p;   p += (size_t)(B + 1) * sizeof(int);

    // ---- CSR build (once; same edge set for all 4 layers) ----
    chunk_hist  <<<NBLK, 256, 0, stream>>>(dsts, E, B, cnt2D);
    chunk_scan  <<<B, 256, 0, stream>>>(cnt2D, NBLK, B, off2D, bcnt);
    bucket_scan <<<1, 1024, 0, stream>>>(bcnt, B, E, bstart, rowptr, N);
    pair_scatter2<<<NBLK, 256, 0, stream>>>(srcs, dsts, E, B, off2D, bstart, pairs);
    bucket_sort <<<B, 256, 0, stream>>>(pairs, bstart, rowptr, csrsrc, N);

    const float* W1   = (const float*)d_in[3];
    const float* as1  = (const float*)d_in[4];
    const float* ad1  = (const float*)d_in[5];
    const float* b1   = (const float*)d_in[6];
    const float* W2   = (const float*)d_in[7];
    const float* as2  = (const float*)d_in[8];
    const float* ad2  = (const float*)d_in[9];
    const float* b2   = (const float*)d_in[10];
    const float* W3   = (const float*)d_in[11];
    const float* as3  = (const float*)d_in[12];
    const float* ad3  = (const float*)d_in[13];
    const float* b3   = (const float*)d_in[14];
    const float* W4   = (const float*)d_in[15];
    const float* as4  = (const float*)d_in[16];
    const float* ad4  = (const float*)d_in[17];
    const float* b4   = (const float*)d_in[18];

    const int aggGrid = (N * 4 + 255) / 256;

    // layer 1 GEMM (MFMA), then 4 fused agg(+next-GEMM) kernels
    gemm_mfma<IN_DIM><<<ntiles, 256, 0, stream>>>(x, W1, h_a, N);
    agg_fused<false><<<aggGrid, 256, 0, stream>>>(h_a, rowptr, csrsrc, as1, ad1, b1, W2, h_b, xbuf, N);
    agg_fused<false><<<aggGrid, 256, 0, stream>>>(h_b, rowptr, csrsrc, as2, ad2, b2, W3, h_a, xbuf, N);
    agg_fused<false><<<aggGrid, 256, 0, stream>>>(h_a, rowptr, csrsrc, as3, ad3, b3, W4, h_b, xbuf, N);
    agg_fused<true> <<<aggGrid, 256, 0, stream>>>(h_b, rowptr, csrsrc, as4, ad4, b4, W4, h_a, xbuf, N);

    // ---- global mean pool: one wave per graph ----
    pool_graph<<<(G * 64 + 255) / 256, 256, 0, stream>>>(xbuf, batch, (float*)d_out, N, G);
}